// Round 2
// baseline (1734.082 us; speedup 1.0000x reference)
//
#include <hip/hip_runtime.h>
#include <hip/hip_bf16.h>

typedef unsigned short u16;
typedef unsigned int u32;
typedef __attribute__((ext_vector_type(8))) short short8;
typedef __attribute__((ext_vector_type(4))) float f32x4;

#define DEV static __device__ __forceinline__

DEV u16 f2bf(float f) {
  u32 x = __float_as_uint(f);
  u32 r = x + 0x7fffu + ((x >> 16) & 1u);   // RNE
  return (u16)(r >> 16);
}
DEV float bf2f(u16 u) { return __uint_as_float(((u32)u) << 16); }
DEV f32x4 fzero() { f32x4 z = {0.f, 0.f, 0.f, 0.f}; return z; }

constexpr int H    = 512;
constexpr int LDA  = 520;                 // padded bf16 row stride (breaks bank alignment)
constexpr int MBLK = 64;                  // rows per WG = 8 samples
constexpr int OFF_T = MBLK * LDA;         // ushort offset of second buffer
constexpr int MISC_OFF = 2 * MBLK * LDA * 2;   // 133120 bytes

struct Misc {
  float P[8][8][8];
  float aArr[64], bArr[64];
  float stats[64][8][2];
  float mu[64], rs[64];
  int ct[8];
  int act[64];
};
constexpr int SMEM_TOTAL = MISC_OFF + (int)sizeof(Misc);

// ---- per-wave GEMM: A (LDS, bf16 [rows][lda]) x Bt (global bf16 [N][ldb]) ----
template<int MT, int NT>
DEV void gemm_k(const u16* A, int lda, const u16* __restrict__ Bt, int ldb,
                int nbase, int klen, int lane, f32x4 acc[MT][NT]) {
  const int ml = lane & 15;
  const int koff = (lane >> 4) * 8;
  #pragma unroll 2
  for (int k0 = 0; k0 < klen; k0 += 32) {
    short8 a[MT];
    short8 b[NT];
    #pragma unroll
    for (int mt = 0; mt < MT; ++mt)
      a[mt] = *(const short8*)(A + (mt * 16 + ml) * lda + k0 + koff);
    #pragma unroll
    for (int nt = 0; nt < NT; ++nt)
      b[nt] = *(const short8*)(Bt + (nbase + nt * 16 + ml) * ldb + k0 + koff);
    #pragma unroll
    for (int mt = 0; mt < MT; ++mt)
      #pragma unroll
      for (int nt = 0; nt < NT; ++nt)
        acc[mt][nt] = __builtin_amdgcn_mfma_f32_16x16x32_bf16(a[mt], b[nt], acc[mt][nt], 0, 0, 0);
  }
}

// =============================== main fused kernel ===============================
__global__ __launch_bounds__(512, 2) void fused_main(
    const float* __restrict__ x,
    const int* __restrict__ ctype,
    const void* __restrict__ cact,
    const float* __restrict__ ctbias,
    const float* __restrict__ ln1g, const float* __restrict__ ln1b,
    const float* __restrict__ ln2g, const float* __restrict__ ln2b,
    const float* __restrict__ b1, const float* __restrict__ b2,
    const float* __restrict__ boc,
    const float* __restrict__ Zp, const float* __restrict__ u2v, const float* __restrict__ s4,
    const u16* __restrict__ M8t, const u16* __restrict__ W6t,
    const u16* __restrict__ W1t, const u16* __restrict__ W2t,
    const int* __restrict__ flagp,
    float* __restrict__ out) {
  extern __shared__ __align__(16) char smem[];
  u16* bufN = (u16*)smem;
  u16* bufT = bufN + OFF_T;
  Misc* ms = (Misc*)(smem + MISC_OFF);

  const int tid = threadIdx.x;
  const int lane = tid & 63;
  const int w = tid >> 6;
  const int wg = blockIdx.x;
  const int row0 = wg * MBLK;
  const int ml = lane & 15, rg = lane >> 4;

  // stage cancer_type + channel_active (dtype-flag aware)
  if (tid < 8) ms->ct[tid] = ctype[wg * 8 + tid];
  if (tid >= 64 && tid < 128) {
    int i = tid - 64;
    int gi = wg * 64 + i;
    int a;
    if (*flagp) a = (int)((const unsigned char*)cact)[gi];
    else        a = ((const int*)cact)[gi];
    ms->act[i] = a;
  }

  // ---------------- LN1: x -> normed(bufN) ----------------
  {
    const int r = tid >> 3, seg = tid & 7;
    const float* xr = x + (size_t)(row0 + r) * H + seg * 64;
    float4 v[16];
    float sum = 0.f, ss = 0.f;
    #pragma unroll
    for (int i = 0; i < 16; ++i) {
      v[i] = ((const float4*)xr)[i];
      sum += v[i].x + v[i].y + v[i].z + v[i].w;
      ss  += v[i].x * v[i].x + v[i].y * v[i].y + v[i].z * v[i].z + v[i].w * v[i].w;
    }
    #pragma unroll
    for (int m = 1; m < 8; m <<= 1) { sum += __shfl_xor(sum, m); ss += __shfl_xor(ss, m); }
    const float mu = sum * (1.f / 512.f);
    const float rstd = rsqrtf(ss * (1.f / 512.f) - mu * mu + 1e-5f);
    const float* g = ln1g + seg * 64;
    const float* bb = ln1b + seg * 64;
    u16* dst = bufN + r * LDA + seg * 64;
    #pragma unroll
    for (int i = 0; i < 16; ++i) {
      float f0 = (v[i].x - mu) * rstd * g[i * 4 + 0] + bb[i * 4 + 0];
      float f1 = (v[i].y - mu) * rstd * g[i * 4 + 1] + bb[i * 4 + 1];
      float f2 = (v[i].z - mu) * rstd * g[i * 4 + 2] + bb[i * 4 + 2];
      float f3 = (v[i].w - mu) * rstd * g[i * 4 + 3] + bb[i * 4 + 3];
      ushort4 o; o.x = f2bf(f0); o.y = f2bf(f1); o.z = f2bf(f2); o.w = f2bf(f3);
      *(ushort4*)(dst + i * 4) = o;
    }
  }
  __syncthreads();

  // ---------------- GEMM1: T = normed @ M8  -> bufT ----------------
  {
    f32x4 acc[4][4];
    #pragma unroll
    for (int mt = 0; mt < 4; ++mt)
      #pragma unroll
      for (int nt = 0; nt < 4; ++nt) acc[mt][nt] = fzero();
    gemm_k<4, 4>(bufN, LDA, M8t, 512, w * 64, 512, lane, acc);
    #pragma unroll
    for (int mt = 0; mt < 4; ++mt)
      #pragma unroll
      for (int nt = 0; nt < 4; ++nt)
        #pragma unroll
        for (int r = 0; r < 4; ++r) {
          int row = mt * 16 + rg * 4 + r;
          int col = w * 64 + nt * 16 + ml;
          bufT[row * LDA + col] = f2bf(acc[mt][nt][r]);
        }
  }
  __syncthreads();

  // ---------------- per-row dots: a=n.(Z[ct]+u1), b=n.u2 ----------------
  {
    const int r = tid >> 3, seg = tid & 7;
    const int ct = ms->ct[r >> 3];
    const float* zp = Zp + ct * 512 + seg * 64;
    const float* u2p = u2v + seg * 64;
    const u16* np = bufN + r * LDA + seg * 64;
    float av = 0.f, bv = 0.f;
    #pragma unroll
    for (int i = 0; i < 64; ++i) { float f = bf2f(np[i]); av += f * zp[i]; bv += f * u2p[i]; }
    #pragma unroll
    for (int m = 1; m < 8; m <<= 1) { av += __shfl_xor(av, m); bv += __shfl_xor(bv, m); }
    if ((tid & 7) == 0) { ms->aArr[r] = av; ms->bArr[r] = bv; }
  }
  __syncthreads();

  // ---------------- S = T.n^T, bias, mask, softmax (wave w = sample w) ----------------
  {
    const int c = (lane >> 3) & 7, d = lane & 7;
    const u16* tp = bufT + (w * 8 + c) * LDA;
    const u16* np = bufN + (w * 8 + d) * LDA;
    float dot = 0.f;
    for (int i = 0; i < 512; i += 8) {
      short8 a = *(const short8*)(tp + i);
      short8 b = *(const short8*)(np + i);
      #pragma unroll
      for (int j = 0; j < 8; ++j) dot += bf2f((u16)a[j]) * bf2f((u16)b[j]);
    }
    const int ct = ms->ct[w];
    float S = (dot + ms->aArr[w * 8 + c] + ms->bArr[w * 8 + d] + s4[ct]) * 0.04419417382415922f
              + 0.1f * ctbias[ct * 64 + c * 8 + d];
    if (!ms->act[w * 8 + d]) S = -INFINITY;
    float m = S;
    #pragma unroll
    for (int k = 1; k < 8; k <<= 1) m = fmaxf(m, __shfl_xor(m, k));
    float e = expf(S - m);
    float sm = e;
    #pragma unroll
    for (int k = 1; k < 8; k <<= 1) sm += __shfl_xor(sm, k);
    ms->P[w][c][d] = e / sm;
  }
  __syncthreads();

  // ---------------- A2 = P @ normed -> bufT ----------------
  {
    const int r = tid >> 3, seg = tid & 7, s = r >> 3, c = r & 7;
    float Pr[8];
    #pragma unroll
    for (int d = 0; d < 8; ++d) Pr[d] = ms->P[s][c][d];
    u16* dst = bufT + r * LDA + seg * 64;
    #pragma unroll
    for (int ch = 0; ch < 8; ++ch) {
      float av[8] = {0.f, 0.f, 0.f, 0.f, 0.f, 0.f, 0.f, 0.f};
      #pragma unroll
      for (int d = 0; d < 8; ++d) {
        short8 vv = *(const short8*)(bufN + (s * 8 + d) * LDA + seg * 64 + ch * 8);
        float p = Pr[d];
        #pragma unroll
        for (int j = 0; j < 8; ++j) av[j] += p * bf2f((u16)vv[j]);
      }
      short8 o;
      #pragma unroll
      for (int j = 0; j < 8; ++j) o[j] = (short)f2bf(av[j]);
      *(short8*)(dst + ch * 8) = o;
    }
  }
  __syncthreads();

  // ---------------- GEMM2: proj = A2 @ W6 + boc ; x2 = x + proj ----------------
  f32x4 acc2[4][4];
  #pragma unroll
  for (int mt = 0; mt < 4; ++mt)
    #pragma unroll
    for (int nt = 0; nt < 4; ++nt) acc2[mt][nt] = fzero();
  gemm_k<4, 4>(bufT, LDA, W6t, 512, w * 64, 512, lane, acc2);
  {
    #pragma unroll
    for (int mt = 0; mt < 4; ++mt)
      #pragma unroll
      for (int nt = 0; nt < 4; ++nt)
        #pragma unroll
        for (int r = 0; r < 4; ++r) {
          int row = mt * 16 + rg * 4 + r;
          int col = w * 64 + nt * 16 + ml;
          size_t gi = (size_t)(row0 + row) * H + col;
          float v2 = x[gi] + acc2[mt][nt][r] + boc[col];
          out[gi] = v2;                    // stash x2 (f32)
          acc2[mt][nt][r] = v2;
        }
    #pragma unroll
    for (int mt = 0; mt < 4; ++mt)
      #pragma unroll
      for (int r = 0; r < 4; ++r) {
        float s1 = acc2[mt][0][r] + acc2[mt][1][r] + acc2[mt][2][r] + acc2[mt][3][r];
        float s2 = acc2[mt][0][r] * acc2[mt][0][r] + acc2[mt][1][r] * acc2[mt][1][r]
                 + acc2[mt][2][r] * acc2[mt][2][r] + acc2[mt][3][r] * acc2[mt][3][r];
        #pragma unroll
        for (int k = 1; k < 16; k <<= 1) { s1 += __shfl_xor(s1, k); s2 += __shfl_xor(s2, k); }
        if (ml == 0) {
          int row = mt * 16 + rg * 4 + r;
          ms->stats[row][w][0] = s1;
          ms->stats[row][w][1] = s2;
        }
      }
  }
  __syncthreads();
  if (tid < 64) {
    float s1 = 0.f, s2 = 0.f;
    #pragma unroll
    for (int i = 0; i < 8; ++i) { s1 += ms->stats[tid][i][0]; s2 += ms->stats[tid][i][1]; }
    float mu = s1 * (1.f / 512.f);
    ms->mu[tid] = mu;
    ms->rs[tid] = rsqrtf(s2 * (1.f / 512.f) - mu * mu + 1e-5f);
  }
  __syncthreads();
  // LN2 from registers -> h (bufN)
  {
    #pragma unroll
    for (int mt = 0; mt < 4; ++mt)
      #pragma unroll
      for (int nt = 0; nt < 4; ++nt)
        #pragma unroll
        for (int r = 0; r < 4; ++r) {
          int row = mt * 16 + rg * 4 + r;
          int col = w * 64 + nt * 16 + ml;
          float hv = (acc2[mt][nt][r] - ms->mu[row]) * ms->rs[row] * ln2g[col] + ln2b[col];
          bufN[row * LDA + col] = f2bf(hv);
        }
  }
  __syncthreads();

  // ---------------- FFN (two K-halves, persistent facc) ----------------
  f32x4 facc[4][4];
  #pragma unroll
  for (int mt = 0; mt < 4; ++mt)
    #pragma unroll
    for (int nt = 0; nt < 4; ++nt) facc[mt][nt] = fzero();

  {  // FFN1 half A: n in [0,512)
    f32x4 acc[4][4];
    #pragma unroll
    for (int mt = 0; mt < 4; ++mt)
      #pragma unroll
      for (int nt = 0; nt < 4; ++nt) acc[mt][nt] = fzero();
    gemm_k<4, 4>(bufN, LDA, W1t, 512, w * 64, 512, lane, acc);
    #pragma unroll
    for (int mt = 0; mt < 4; ++mt)
      #pragma unroll
      for (int nt = 0; nt < 4; ++nt)
        #pragma unroll
        for (int r = 0; r < 4; ++r) {
          int row = mt * 16 + rg * 4 + r;
          int col = w * 64 + nt * 16 + ml;
          float av = acc[mt][nt][r] + b1[col];
          av = av > 0.f ? av : expm1f(av);
          bufT[row * LDA + col] = f2bf(av);
        }
  }
  __syncthreads();
  gemm_k<4, 4>(bufT, LDA, W2t, 1024, w * 64, 512, lane, facc);   // K = 0..511
  __syncthreads();
  {  // FFN1 half B: n in [512,1024)
    f32x4 acc[4][4];
    #pragma unroll
    for (int mt = 0; mt < 4; ++mt)
      #pragma unroll
      for (int nt = 0; nt < 4; ++nt) acc[mt][nt] = fzero();
    gemm_k<4, 4>(bufN, LDA, W1t + 512 * 512, 512, w * 64, 512, lane, acc);
    #pragma unroll
    for (int mt = 0; mt < 4; ++mt)
      #pragma unroll
      for (int nt = 0; nt < 4; ++nt)
        #pragma unroll
        for (int r = 0; r < 4; ++r) {
          int row = mt * 16 + rg * 4 + r;
          int col = w * 64 + nt * 16 + ml;
          float av = acc[mt][nt][r] + b1[512 + col];
          av = av > 0.f ? av : expm1f(av);
          bufT[row * LDA + col] = f2bf(av);
        }
  }
  __syncthreads();
  gemm_k<4, 4>(bufT, LDA, W2t + 512, 1024, w * 64, 512, lane, facc);  // K = 512..1023

  // final: out = x2 + ffn + b2
  #pragma unroll
  for (int mt = 0; mt < 4; ++mt)
    #pragma unroll
    for (int nt = 0; nt < 4; ++nt)
      #pragma unroll
      for (int r = 0; r < 4; ++r) {
        int row = mt * 16 + rg * 4 + r;
        int col = w * 64 + nt * 16 + ml;
        size_t gi = (size_t)(row0 + row) * H + col;
        out[gi] = out[gi] + facc[mt][nt][r] + b2[col];
      }
}

// =============================== prep kernels ===============================
// M8t[n][k] = sum_h Wq[k][h] * Wk[n][h]   (bf16 out, [512][512])
__global__ void prep_qk(const float* __restrict__ Wq, const float* __restrict__ Wk,
                        u16* __restrict__ M8t) {
  __shared__ float kr[512];
  const int n = blockIdx.x;
  for (int i = threadIdx.x; i < 512; i += 256) kr[i] = Wk[n * 512 + i];
  __syncthreads();
  for (int k = threadIdx.x; k < 512; k += 256) {
    const float4* q4 = (const float4*)(Wq + (size_t)k * 512);
    const float4* v4 = (const float4*)kr;
    float s = 0.f;
    for (int i = 0; i < 128; ++i) {
      float4 a = q4[i], b = v4[i];
      s += a.x * b.x + a.y * b.y + a.z * b.z + a.w * b.w;
    }
    M8t[n * 512 + k] = f2bf(s);
  }
}

// W6t[n][k] = sum_h Wv[k][h] * Wo[h][n]
__global__ void prep_vo(const float* __restrict__ Wv, const float* __restrict__ Wo,
                        u16* __restrict__ W6t) {
  __shared__ float oc[512];
  const int n = blockIdx.x;
  for (int h = threadIdx.x; h < 512; h += 256) oc[h] = Wo[(size_t)h * 512 + n];
  __syncthreads();
  for (int k = threadIdx.x; k < 512; k += 256) {
    const float4* v4 = (const float4*)(Wv + (size_t)k * 512);
    const float4* o4 = (const float4*)oc;
    float s = 0.f;
    for (int i = 0; i < 128; ++i) {
      float4 a = v4[i], b = o4[i];
      s += a.x * b.x + a.y * b.y + a.z * b.z + a.w * b.w;
    }
    W6t[n * 512 + k] = f2bf(s);
  }
}

// transpose + bf16: W [K][N] f32 -> Wt [N][K] bf16
__global__ void prep_tr(const float* __restrict__ W, u16* __restrict__ Wt, int K, int N) {
  __shared__ float t[32][33];
  const int n0 = blockIdx.x * 32, k0 = blockIdx.y * 32;
  const int tx = threadIdx.x & 31, ty = threadIdx.x >> 5;  // ty < 8
  #pragma unroll
  for (int i = 0; i < 32; i += 8) t[ty + i][tx] = W[(size_t)(k0 + ty + i) * N + n0 + tx];
  __syncthreads();
  #pragma unroll
  for (int i = 0; i < 32; i += 8) Wt[(size_t)(n0 + ty + i) * K + k0 + tx] = f2bf(t[tx][ty + i]);
}

// small stuff: Zp[t][k]=sum_h Wq[k][h]*(ctk[t][h]+bk[h]); u2[k]=sum_h bq[h]*Wk[k][h];
// boc[n]=bo[n]+sum_h bv[h]*Wo[h][n]; s4[t]=sum_h bq[h]*(bk[h]+ctk[t][h]); flag=bool-dtype detect
__global__ void prep_small(const float* __restrict__ Wq, const float* __restrict__ Wk,
                           const float* __restrict__ Wo,
                           const float* __restrict__ bq, const float* __restrict__ bk,
                           const float* __restrict__ bv, const float* __restrict__ bo,
                           const float* __restrict__ ctk, const void* __restrict__ cact,
                           float* __restrict__ Zp, float* __restrict__ u2,
                           float* __restrict__ boc, float* __restrict__ s4,
                           int* __restrict__ flag) {
  const int b = blockIdx.x, t = threadIdx.x;
  if (b < 32) {
    __shared__ float v[512];
    v[t] = ctk[b * 512 + t] + bk[t];
    __syncthreads();
    float s = 0.f;
    const float* q = Wq + (size_t)t * 512;
    for (int h = 0; h < 512; ++h) s += q[h] * v[h];
    Zp[b * 512 + t] = s;
  } else if (b == 32) {
    __shared__ float v[512];
    v[t] = bq[t];
    __syncthreads();
    float s = 0.f;
    const float* wk = Wk + (size_t)t * 512;
    for (int h = 0; h < 512; ++h) s += wk[h] * v[h];
    u2[t] = s;
  } else if (b == 33) {
    float s = 0.f;
    for (int h = 0; h < 512; ++h) s += bv[h] * Wo[(size_t)h * 512 + t];
    boc[t] = bo[t] + s;
  } else if (b == 34) {
    if (t < 32) {
      float s = 0.f;
      for (int h = 0; h < 512; ++h) s += bq[h] * (bk[h] + ctk[t * 512 + h]);
      s4[t] = s;
    }
  } else {  // b == 35: detect channel_active dtype. int32 0/1 -> bytes at (i&3)!=0 are all 0.
    if (t == 0) {
      const unsigned char* p = (const unsigned char*)cact;
      int f = 0;
      for (int i = 0; i < 1024; ++i)
        if ((i & 3) != 0 && p[i] != 0) f = 1;
      *flag = f;   // 1 => 1-byte bool, 0 => int32
    }
  }
}

// =============================== launch ===============================
extern "C" void kernel_launch(void* const* d_in, const int* in_sizes, int n_in,
                              void* d_out, int out_size, void* d_ws, size_t ws_size,
                              hipStream_t stream) {
  (void)in_sizes; (void)n_in; (void)out_size; (void)ws_size;
  const float* x     = (const float*)d_in[0];
  const int*   ctype = (const int*)d_in[1];
  const void*  cact  = d_in[2];
  const float* Wq = (const float*)d_in[3];
  const float* bq = (const float*)d_in[4];
  const float* Wk = (const float*)d_in[5];
  const float* bk = (const float*)d_in[6];
  const float* Wv = (const float*)d_in[7];
  const float* bv = (const float*)d_in[8];
  const float* Wo = (const float*)d_in[9];
  const float* bo = (const float*)d_in[10];
  const float* ctbias = (const float*)d_in[11];
  const float* ctk    = (const float*)d_in[12];
  const float* ln1g = (const float*)d_in[13];
  const float* ln1b = (const float*)d_in[14];
  const float* ln2g = (const float*)d_in[15];
  const float* ln2b = (const float*)d_in[16];
  const float* W1 = (const float*)d_in[17];
  const float* b1 = (const float*)d_in[18];
  const float* W2 = (const float*)d_in[19];
  const float* b2 = (const float*)d_in[20];

  char* ws = (char*)d_ws;
  u16* M8t = (u16*)(ws + 0);                  // 512*512*2 = 524288
  u16* W6t = (u16*)(ws + 524288);             // 524288
  u16* W1t = (u16*)(ws + 1048576);            // 1024*512*2 = 1048576
  u16* W2t = (u16*)(ws + 2097152);            // 1048576
  float* Zp  = (float*)(ws + 3145728);        // 32*512*4 = 65536
  float* u2  = (float*)(ws + 3211264);        // 2048
  float* boc = (float*)(ws + 3213312);        // 2048
  float* s4  = (float*)(ws + 3215360);        // 128
  int*   flag = (int*)(ws + 3215488);

  prep_qk<<<512, 256, 0, stream>>>(Wq, Wk, M8t);
  prep_vo<<<512, 256, 0, stream>>>(Wv, Wo, W6t);
  { dim3 g(1024 / 32, 512 / 32);  prep_tr<<<g, 256, 0, stream>>>(W1, W1t, 512, 1024); }
  { dim3 g(512 / 32, 1024 / 32);  prep_tr<<<g, 256, 0, stream>>>(W2, W2t, 1024, 512); }
  prep_small<<<36, 512, 0, stream>>>(Wq, Wk, Wo, bq, bk, bv, bo, ctk, cact,
                                     Zp, u2, boc, s4, flag);

  hipFuncSetAttribute((const void*)fused_main,
                      hipFuncAttributeMaxDynamicSharedMemorySize, SMEM_TOTAL);
  fused_main<<<2048, 512, SMEM_TOTAL, stream>>>(
      x, ctype, cact, ctbias, ln1g, ln1b, ln2g, ln2b, b1, b2, boc,
      Zp, u2, s4, M8t, W6t, W1t, W2t, flag, (float*)d_out);
}